// Round 11
// baseline (918.077 us; speedup 1.0000x reference)
//
#include <hip/hip_runtime.h>
#include <hip/hip_bf16.h>
#include <utility>

#define BB 16
#define CC 16
#define HH 384
#define WW 384
#define HWSZ (HH*WW)
#define CHW (CC*HWSZ)
#define NPIX (BB*CHW)

#define FT 224             // 16 ch x 14 staged 8-col groups
#define ROWS 12            // rows per block
#define HSEGS (HH/ROWS)    // 32
#define NSTRIP 4           // W split into 4 x 96-col output strips
#define SWOUT 96
#define SG 14              // staged groups (112 cols = 96 out + 8 halo each side)
#define SGO 12             // output groups
#define PLW 120            // LDS plane width (u16): 112 used + 8 bank-pad

typedef unsigned short ushortT;
template<int N> using ic = std::integral_constant<int, N>;

// ---- bf16 helpers ---------------------------------------------------------
__device__ __forceinline__ void unpk2(unsigned u, float& lo, float& hi) {
    union { unsigned u; float f; } a, b;
    a.u = u << 16; b.u = u & 0xFFFF0000u;
    lo = a.f; hi = b.f;
}
__device__ __forceinline__ unsigned pk2(float lo, float hi) {
    __hip_bfloat162 h = __float22bfloat162_rn(make_float2(lo, hi));
    union { __hip_bfloat162 h; unsigned u; } c; c.h = h;
    return c.u;
}
__device__ __forceinline__ void unpk8(const uint4& q, float* v) {
    unpk2(q.x, v[0], v[1]); unpk2(q.y, v[2], v[3]);
    unpk2(q.z, v[4], v[5]); unpk2(q.w, v[6], v[7]);
}
__device__ __forceinline__ uint4 pk8(const float* v) {
    uint4 q;
    q.x = pk2(v[0], v[1]); q.y = pk2(v[2], v[3]);
    q.z = pk2(v[4], v[5]); q.w = pk2(v[6], v[7]);
    return q;
}
template<int CTRL>
__device__ __forceinline__ float dpp_f(float x) {
    union { float f; int i; } c; c.f = x;
    union { int i; float f; } r;
    r.i = __builtin_amdgcn_update_dpp(0, c.i, CTRL, 0xF, 0xF, true);
    return r.f;
}

// ---------------------------------------------------------------------------
// Strip-parallel fused CRF step.  Block = (b, 12-row band, 96-col strip),
// 224 threads (4 waves).  Staged range = strip +- 8-col halo (recompute).
//  MODE 0: in0 = x0 (f32); emits x0b (bf16) and t0.
//  MODE 1: in0 = t_n (bf16) + x0b; emits t_{n+1}.
//  MODE 2: in0 = t_4 (bf16) + x0b; emits log_softmax(x5) f32.
// Per row-pair: {loads; C(prev pair); A ConvH->LDS} bar {B softmax} bar.
// Image-edge cols handled by zeroing p (masked 1/s) => matches zero-pad conv.
// ---------------------------------------------------------------------------
template<int MODE>
__global__ __launch_bounds__(FT, 4) void k_fused(
    const void* __restrict__ in0, const ushortT* __restrict__ x0b,
    void* __restrict__ outp, ushortT* __restrict__ x0b_out,
    const float* __restrict__ spacings, const float* __restrict__ invtheta,
    const float* __restrict__ swp)
{
    __shared__ ushortT xp[4][CC][PLW];   // 4 row-bufs, 15360 B
    __shared__ float l_lds[4][112];      // MODE 2 only

    const int t  = threadIdx.x;
    const int b  = blockIdx.z;
    const int h0 = blockIdx.x * ROWS;
    const int W0 = blockIdx.y * SWOUT;

    const float sw  = swp[0];
    const float sch = spacings[b * 2 + 0] * invtheta[0];   // H axis
    const float scw = spacings[b * 2 + 1] * invtheta[1];   // W axis
    float kh[5], kw[5];                                    // symmetric taps
#pragma unroll
    for (int j = 0; j < 5; ++j) {
        float dh = sch * (float)(j - 5); kh[j] = __expf(-0.5f * dh * dh);
        float dw = scw * (float)(j - 5); kw[j] = __expf(-0.5f * dw * dw);
    }

    const int ca = t / SG,  ga = t - (t / SG) * SG;     // A identity
    const int cp = t >> 2,  qq = t & 3;                 // B identity (col-pair, ch-quad)
    const int co = t / SGO, go = t - (t / SGO) * SGO;   // C identity
    const bool cAct = (t < CC * SGO);                   // 192 active in C

    const int  gw    = W0 - 8 + ga * 8;                 // staged group start col
    const bool colOK = ((unsigned)gw < WW);             // groups fully in/out (8-aligned)
    const long long cbase = (long long)(b * CC + ca) * HWSZ + gw;
    const uint4 z4 = make_uint4(0u, 0u, 0u, 0u);

    // rolling t-window (MODE>=1): slot s holds row h0-5+s (cyclic)
    uint4 win[12];
    if constexpr (MODE >= 1) {
        const ushortT* tin = (const ushortT*)in0;
#pragma unroll
        for (int s = 0; s < 12; ++s) {
            const int r = h0 - 5 + s;
            win[s] = (colOK && (unsigned)r < HH)
                ? *(const uint4*)(tin + cbase + (long long)r * WW) : z4;
        }
    }

    // ---- A: ConvH (static slots) + x0b add -> LDS bf16 ----
    auto A_conv = [&](auto K0c, int buf, const uint4& uq) {
        constexpr int k0 = decltype(K0c)::value;
        float acc[8];
#pragma unroll
        for (int k = 0; k < 8; ++k) acc[k] = 0.f;
#pragma unroll
        for (int j = 0; j < 5; ++j) {
            constexpr int dummy = 0; (void)dummy;
            const int sa = (k0 + j) % 12;        // folds: k0 constexpr, j unrolled
            const int sb = (k0 + 10 - j) % 12;
            float e1[8], e2[8];
            unpk8(win[sa], e1); unpk8(win[sb], e2);
            const float kj = kh[j];
#pragma unroll
            for (int k = 0; k < 8; ++k) acc[k] = fmaf(kj, e1[k] + e2[k], acc[k]);
        }
        float uu[8]; unpk8(uq, uu);
        float xv[8];
#pragma unroll
        for (int k = 0; k < 8; ++k) xv[k] = fmaf(sw, acc[k], uu[k]);
        *(uint4*)&xp[buf][ca][ga * 8] = pk8(xv);
    };

    auto A_m0 = [&](int h, int buf) {
        const float* xf = (const float*)in0;
        float v[8];
        if (colOK) {
            const float4 A0 = *(const float4*)(xf + cbase + (long long)h * WW);
            const float4 A1 = *(const float4*)(xf + cbase + (long long)h * WW + 4);
            v[0]=A0.x; v[1]=A0.y; v[2]=A0.z; v[3]=A0.w;
            v[4]=A1.x; v[5]=A1.y; v[6]=A1.z; v[7]=A1.w;
        } else {
#pragma unroll
            for (int k = 0; k < 8; ++k) v[k] = 0.f;
        }
        const uint4 q = pk8(v);
        if (ga >= 1 && ga <= SGO)   // output groups only: each col written exactly once
            *(uint4*)(x0b_out + cbase + (long long)h * WW) = q;
        *(uint4*)&xp[buf][ca][ga * 8] = q;
    };

    // ---- B: per-column softmax; DPP quad reduce over 16 channels ----
    auto B_row = [&](int buf) {
        float xa[4], xb[4];
#pragma unroll
        for (int i = 0; i < 4; ++i) {
            const unsigned u = *(const unsigned*)&xp[buf][qq * 4 + i][2 * cp];
            unpk2(u, xa[i], xb[i]);
        }
        float m0 = fmaxf(fmaxf(xa[0], xa[1]), fmaxf(xa[2], xa[3]));
        float m1 = fmaxf(fmaxf(xb[0], xb[1]), fmaxf(xb[2], xb[3]));
        m0 = fmaxf(m0, dpp_f<0xB1>(m0)); m0 = fmaxf(m0, dpp_f<0x4E>(m0));
        m1 = fmaxf(m1, dpp_f<0xB1>(m1)); m1 = fmaxf(m1, dpp_f<0x4E>(m1));
        float e0[4], e1[4], s0 = 0.f, s1 = 0.f;
#pragma unroll
        for (int i = 0; i < 4; ++i) {
            e0[i] = __expf(xa[i] - m0); s0 += e0[i];
            e1[i] = __expf(xb[i] - m1); s1 += e1[i];
        }
        s0 += dpp_f<0xB1>(s0); s0 += dpp_f<0x4E>(s0);
        s1 += dpp_f<0xB1>(s1); s1 += dpp_f<0x4E>(s1);
        if constexpr (MODE <= 1) {
            // zero p for out-of-image cols (masked 1/s) == reference zero-pad
            const float i0 = ((unsigned)(W0 - 8 + 2 * cp)     < WW) ? 1.0f / s0 : 0.f;
            const float i1 = ((unsigned)(W0 - 8 + 2 * cp + 1) < WW) ? 1.0f / s1 : 0.f;
#pragma unroll
            for (int i = 0; i < 4; ++i)
                *(unsigned*)&xp[buf][qq * 4 + i][2 * cp] = pk2(e0[i] * i0, e1[i] * i1);
        } else {
            if (qq == 0) {
                l_lds[buf][2 * cp]     = m0 + __logf(s0);
                l_lds[buf][2 * cp + 1] = m1 + __logf(s1);
            }
        }
    };

    // ---- C: ConvW -> t' (bf16) / final log_softmax out (f32) ----
    auto C_row = [&](int h, int buf) {
        if constexpr (MODE <= 1) {
            const uint4 q0 = *(const uint4*)&xp[buf][co][go * 8];
            const uint4 q1 = *(const uint4*)&xp[buf][co][go * 8 + 8];
            const uint4 q2 = *(const uint4*)&xp[buf][co][go * 8 + 16];
            float w[24];
            unpk8(q0, w); unpk8(q1, w + 8); unpk8(q2, w + 16);
            float o[8];
#pragma unroll
            for (int k = 0; k < 8; ++k) {
                float a = 0.f;
#pragma unroll
                for (int j = 0; j < 5; ++j)
                    a = fmaf(kw[j], w[k + 3 + j] + w[k + 13 - j], a);
                o[k] = a;
            }
            *(uint4*)((ushortT*)outp + (long long)(b * CC + co) * HWSZ
                      + (long long)h * WW + W0 + go * 8) = pk8(o);
        } else {
            const uint4 xq = *(const uint4*)&xp[buf][co][8 + go * 8];
            float xv[8]; unpk8(xq, xv);
            const float4 l0 = *(const float4*)&l_lds[buf][8 + go * 8];
            const float4 l1 = *(const float4*)&l_lds[buf][8 + go * 8 + 4];
            float* op = (float*)outp + (long long)(b * CC + co) * HWSZ
                        + (long long)h * WW + W0 + go * 8;
            *(float4*)op       = make_float4(xv[0]-l0.x, xv[1]-l0.y, xv[2]-l0.z, xv[3]-l0.w);
            *(float4*)(op + 4) = make_float4(xv[4]-l1.x, xv[5]-l1.y, xv[6]-l1.z, xv[7]-l1.w);
        }
    };

    auto pair_body = [&](auto Pc) {
        constexpr int p = decltype(Pc)::value;
        const int h = h0 + 2 * p;
        constexpr int bA = 2 * (p & 1);
        constexpr int bC = bA ^ 2;

        if constexpr (MODE == 0) {
            if (p > 0 && cAct) { C_row(h - 2, bC); C_row(h - 1, bC | 1); }
            A_m0(h, bA); A_m0(h + 1, bA | 1);
        } else {
            const ushortT* tin = (const ushortT*)in0;
            const uint4 uq0 = colOK ? *(const uint4*)(x0b + cbase + (long long)h * WW) : z4;
            const uint4 uq1 = colOK ? *(const uint4*)(x0b + cbase + (long long)(h + 1) * WW) : z4;
            uint4 nt0 = z4, nt1 = z4;
            if (p < 5) {
                const int r0 = h + 7, r1 = h + 8;
                if (colOK && r0 < HH) nt0 = *(const uint4*)(tin + cbase + (long long)r0 * WW);
                if (colOK && r1 < HH) nt1 = *(const uint4*)(tin + cbase + (long long)r1 * WW);
            }
            if (p > 0 && cAct) { C_row(h - 2, bC); C_row(h - 1, bC | 1); }
            A_conv(ic<(2 * p) % 12>{},     bA,     uq0);
            A_conv(ic<(2 * p + 1) % 12>{}, bA | 1, uq1);
            if (p < 5) { win[(2 * p) % 12] = nt0; win[(2 * p + 1) % 12] = nt1; }
        }
        __syncthreads();
        B_row(bA);
        B_row(bA | 1);
        __syncthreads();
    };

    pair_body(ic<0>{}); pair_body(ic<1>{}); pair_body(ic<2>{});
    pair_body(ic<3>{}); pair_body(ic<4>{}); pair_body(ic<5>{});

    if (cAct) { C_row(h0 + 10, 2); C_row(h0 + 11, 3); }
}

// ---------------------------------------------------------------------------
extern "C" void kernel_launch(void* const* d_in, const int* in_sizes, int n_in,
                              void* d_out, int out_size, void* d_ws, size_t ws_size,
                              hipStream_t stream)
{
    const float* x0   = (const float*)d_in[0];  // (B,C,H,W) f32
    const float* spac = (const float*)d_in[1];  // (B,2)
    const float* sw   = (const float*)d_in[2];  // scalar
    const float* it   = (const float*)d_in[3];  // (2,)

    ushortT* tA  = (ushortT*)d_ws;              // 75.5 MB
    ushortT* tB  = tA + (size_t)NPIX;           // 75.5 MB
    ushortT* x0b = tB + (size_t)NPIX;           // 75.5 MB
    float*   out = (float*)d_out;

    dim3 gf(HSEGS, NSTRIP, BB);   // (32, 4, 16) = 2048 blocks, 4 waves each
    dim3 bf(FT);

    // iter 1: t0 = ConvW(softmax(x0)); also emits x0b
    k_fused<0><<<gf, bf, 0, stream>>>(x0, nullptr, tA, x0b, spac, it, sw);
    // iters 2..5: t_{n+1} = ConvW(softmax(x0b + sw*ConvH(t_n)))
    k_fused<1><<<gf, bf, 0, stream>>>(tA, x0b, tB, nullptr, spac, it, sw);
    k_fused<1><<<gf, bf, 0, stream>>>(tB, x0b, tA, nullptr, spac, it, sw);
    k_fused<1><<<gf, bf, 0, stream>>>(tA, x0b, tB, nullptr, spac, it, sw);
    k_fused<1><<<gf, bf, 0, stream>>>(tB, x0b, tA, nullptr, spac, it, sw);
    // final: out = log_softmax(x0b + sw*ConvH(t4))
    k_fused<2><<<gf, bf, 0, stream>>>(tA, x0b, out, nullptr, spac, it, sw);
}

// Round 12
// 422.238 us; speedup vs baseline: 2.1743x; 2.1743x over previous
//
#include <hip/hip_runtime.h>
#include <hip/hip_bf16.h>
#include <utility>

#define BB 16
#define CC 16
#define HH 384
#define WW 384
#define HWSZ (HH*WW)
#define CHW (CC*HWSZ)
#define NPIX (BB*CHW)

#define FT 768             // 16 channels x 48 col-groups
#define ROWS 12            // rows per block -> 32x16 = 512 blocks
#define HSEGS (HH/ROWS)
#define SROW 408           // LDS row: 8 pad | 384 | 16 pad (bf16 elems)

typedef unsigned short ushortT;
template<int N> using ic = std::integral_constant<int, N>;

// ---- bf16 helpers ---------------------------------------------------------
__device__ __forceinline__ void unpk2(unsigned u, float& lo, float& hi) {
    union { unsigned u; float f; } a, b;
    a.u = u << 16; b.u = u & 0xFFFF0000u;
    lo = a.f; hi = b.f;
}
__device__ __forceinline__ unsigned pk2(float lo, float hi) {
    __hip_bfloat162 h = __float22bfloat162_rn(make_float2(lo, hi));
    union { __hip_bfloat162 h; unsigned u; } c; c.h = h;
    return c.u;
}
__device__ __forceinline__ void unpk8(const uint4& q, float* v) {
    unpk2(q.x, v[0], v[1]); unpk2(q.y, v[2], v[3]);
    unpk2(q.z, v[4], v[5]); unpk2(q.w, v[6], v[7]);
}
__device__ __forceinline__ uint4 pk8(const float* v) {
    uint4 q;
    q.x = pk2(v[0], v[1]); q.y = pk2(v[2], v[3]);
    q.z = pk2(v[4], v[5]); q.w = pk2(v[6], v[7]);
    return q;
}
template<int CTRL>
__device__ __forceinline__ float dpp_f(float x) {
    union { float f; int i; } c; c.f = x;
    union { int i; float f; } r;
    r.i = __builtin_amdgcn_update_dpp(0, c.i, CTRL, 0xF, 0xF, true);
    return r.f;
}

// ---------------------------------------------------------------------------
// Fused CRF step (R9 structure + 1-pair-deep x0b prefetch).
//  MODE 0: in0 = x0 (f32); emits x0b (bf16) and t0.
//  MODE 1: in0 = t_n (bf16) + x0b; emits t_{n+1}.
//  MODE 2: in0 = t_4 (bf16) + x0b; emits log_softmax(x5) f32.
// ---------------------------------------------------------------------------
template<int MODE>
__global__ __launch_bounds__(FT, 3) void k_fused(
    const void* __restrict__ in0, const ushortT* __restrict__ x0b,
    void* __restrict__ outp, ushortT* __restrict__ x0b_out,
    const float* __restrict__ spacings, const float* __restrict__ invtheta,
    const float* __restrict__ swp)
{
    __shared__ ushortT xp[4][CC][SROW];          // 52224 B
    __shared__ __align__(16) float l_lds[2][WW]; // MODE 2 only

    const int t  = threadIdx.x;
    const int b  = blockIdx.y;
    const int h0 = blockIdx.x * ROWS;

    {   // zero pads: 4 buf x 16 ch x 12 u32-slots = 768 threads, one each
        const int buf = t / (CC * 12);
        const int rem = t - buf * (CC * 12);
        const int c = rem / 12, s = rem - (rem / 12) * 12;
        const int e = (s < 4) ? (2 * s) : (392 + 2 * (s - 4));
        *(unsigned*)&xp[buf][c][e] = 0u;
    }

    const float sw  = swp[0];
    const float sch = spacings[b * 2 + 0] * invtheta[0];   // H axis
    const float scw = spacings[b * 2 + 1] * invtheta[1];   // W axis
    float kh[5], kw[5];                                    // symmetric taps
#pragma unroll
    for (int j = 0; j < 5; ++j) {
        float dh = sch * (float)(j - 5); kh[j] = __expf(-0.5f * dh * dh);
        float dw = scw * (float)(j - 5); kw[j] = __expf(-0.5f * dw * dw);
    }

    const int ca = t / 48, ga = t - (t / 48) * 48;   // A/C identity
    const int cp = t >> 2, qq = t & 3;               // B identity

    const size_t cbase = (size_t)b * CHW + (size_t)ca * HWSZ + (size_t)ga * 8;
    const uint4 z4 = make_uint4(0u, 0u, 0u, 0u);

    // rolling t-window: slot s holds t-row (h0-5+s), cyclic; packed bf16
    uint4 W[12];
    // x0b row prefetch (1 pair deep)
    uint4 uq0 = z4, uq1 = z4;
    if (MODE >= 1) {
        const ushortT* tin = (const ushortT*)in0;
#pragma unroll
        for (int j = 0; j < 12; ++j) {
            const int r = h0 + j - 5;
            W[j] = ((unsigned)r < HH) ? *(const uint4*)(tin + cbase + (size_t)r * WW) : z4;
        }
        uq0 = *(const uint4*)(x0b + cbase + (size_t)h0 * WW);
        uq1 = *(const uint4*)(x0b + cbase + (size_t)(h0 + 1) * WW);
    }

    __syncthreads();   // pads visible

    auto B_row = [&](int buf, int r) {
        float xa[4], xb[4];
#pragma unroll
        for (int i = 0; i < 4; ++i) {
            const unsigned u = *(const unsigned*)&xp[buf][qq * 4 + i][8 + 2 * cp];
            unpk2(u, xa[i], xb[i]);
        }
        float m0 = fmaxf(fmaxf(xa[0], xa[1]), fmaxf(xa[2], xa[3]));
        float m1 = fmaxf(fmaxf(xb[0], xb[1]), fmaxf(xb[2], xb[3]));
        m0 = fmaxf(m0, dpp_f<0xB1>(m0)); m0 = fmaxf(m0, dpp_f<0x4E>(m0));
        m1 = fmaxf(m1, dpp_f<0xB1>(m1)); m1 = fmaxf(m1, dpp_f<0x4E>(m1));
        float e0[4], e1[4], s0 = 0.f, s1 = 0.f;
#pragma unroll
        for (int i = 0; i < 4; ++i) {
            e0[i] = __expf(xa[i] - m0); s0 += e0[i];
            e1[i] = __expf(xb[i] - m1); s1 += e1[i];
        }
        s0 += dpp_f<0xB1>(s0); s0 += dpp_f<0x4E>(s0);
        s1 += dpp_f<0xB1>(s1); s1 += dpp_f<0x4E>(s1);
        if (MODE <= 1) {
            const float i0 = 1.0f / s0, i1 = 1.0f / s1;
#pragma unroll
            for (int i = 0; i < 4; ++i)
                *(unsigned*)&xp[buf][qq * 4 + i][8 + 2 * cp] = pk2(e0[i] * i0, e1[i] * i1);
        } else {
            if (qq == 0) {
                l_lds[r][2 * cp]     = m0 + __logf(s0);
                l_lds[r][2 * cp + 1] = m1 + __logf(s1);
            }
        }
    };

    auto C_row = [&](int h, int buf, int r) {
        if (MODE <= 1) {
            const uint4 q0 = *(const uint4*)&xp[buf][ca][ga * 8];
            const uint4 q1 = *(const uint4*)&xp[buf][ca][ga * 8 + 8];
            const uint4 q2 = *(const uint4*)&xp[buf][ca][ga * 8 + 16];
            float w[24];
            unpk8(q0, w); unpk8(q1, w + 8); unpk8(q2, w + 16);
            float o[8];
#pragma unroll
            for (int k = 0; k < 8; ++k) {
                float a = 0.f;
#pragma unroll
                for (int j = 0; j < 5; ++j)
                    a = fmaf(kw[j], w[k + 3 + j] + w[k + 13 - j], a);
                o[k] = a;
            }
            *(uint4*)((ushortT*)outp + cbase + (size_t)h * WW) = pk8(o);
        } else {
            const uint4 xq = *(const uint4*)&xp[buf][ca][8 + ga * 8];
            float xv[8]; unpk8(xq, xv);
            const float4 l0 = *(const float4*)&l_lds[r][ga * 8];
            const float4 l1 = *(const float4*)&l_lds[r][ga * 8 + 4];
            float* op = (float*)outp + cbase + (size_t)h * WW;
            *(float4*)op       = make_float4(xv[0]-l0.x, xv[1]-l0.y, xv[2]-l0.z, xv[3]-l0.w);
            *(float4*)(op + 4) = make_float4(xv[4]-l1.x, xv[5]-l1.y, xv[6]-l1.z, xv[7]-l1.w);
        }
    };

    // ConvH row from static window slots + prefetched x0b row -> LDS
    auto A_row = [&](auto K0c, int buf, const uint4& uq) {
        constexpr int k0 = decltype(K0c)::value;
        float acc[8];
#pragma unroll
        for (int k = 0; k < 8; ++k) acc[k] = 0.f;
#pragma unroll
        for (int j = 0; j < 5; ++j) {
            const int sa = (k0 + j) % 12;        // folds: k0 constexpr, j unrolled
            const int sb = (k0 + 10 - j) % 12;
            float e1[8], e2[8];
            unpk8(W[sa], e1); unpk8(W[sb], e2);
            const float kj = kh[j];
#pragma unroll
            for (int k = 0; k < 8; ++k)
                acc[k] = fmaf(kj, e1[k] + e2[k], acc[k]);
        }
        float uu[8]; unpk8(uq, uu);
        float xv[8];
#pragma unroll
        for (int k = 0; k < 8; ++k) xv[k] = fmaf(sw, acc[k], uu[k]);
        *(uint4*)&xp[buf][ca][8 + ga * 8] = pk8(xv);
    };

    auto A_row_m0 = [&](int h, int buf) {
        const float* xf = (const float*)in0;
        const float4 A0 = *(const float4*)(xf + cbase + (size_t)h * WW);
        const float4 A1 = *(const float4*)(xf + cbase + (size_t)h * WW + 4);
        float v[8] = {A0.x, A0.y, A0.z, A0.w, A1.x, A1.y, A1.z, A1.w};
        const uint4 q = pk8(v);
        *(uint4*)(x0b_out + cbase + (size_t)h * WW) = q;
        *(uint4*)&xp[buf][ca][8 + ga * 8] = q;
    };

    auto pair_body = [&](auto Pc) {
        constexpr int p = decltype(Pc)::value;
        const int h  = h0 + 2 * p;
        constexpr int bA = 2 * (p & 1);
        constexpr int bC = 2 * ((p & 1) ^ 1);

        if (MODE == 0) {
            if (p > 0) { C_row(h - 2, bC, 0); C_row(h - 1, bC + 1, 1); }
            A_row_m0(h, bA); A_row_m0(h + 1, bA + 1);
        } else {
            const ushortT* tin = (const ushortT*)in0;
            // issue ALL of next pair's loads first: t-window rows + x0b rows.
            // consumed only after the next barrier pair -> full-pair latency hiding.
            uint4 nt0 = z4, nt1 = z4, uqn0 = z4, uqn1 = z4;
            if (p < 5) {
                const int r0 = h + 7, r1 = h + 8;
                if (r0 < HH) nt0 = *(const uint4*)(tin + cbase + (size_t)r0 * WW);
                if (r1 < HH) nt1 = *(const uint4*)(tin + cbase + (size_t)r1 * WW);
                uqn0 = *(const uint4*)(x0b + cbase + (size_t)(h + 2) * WW);
                uqn1 = *(const uint4*)(x0b + cbase + (size_t)(h + 3) * WW);
            }
            if (p > 0) { C_row(h - 2, bC, 0); C_row(h - 1, bC + 1, 1); }
            A_row(ic<(2 * p) % 12>{},     bA,     uq0);
            A_row(ic<(2 * p + 1) % 12>{}, bA + 1, uq1);
            if (p < 5) {
                W[(2 * p) % 12]     = nt0;
                W[(2 * p + 1) % 12] = nt1;
                uq0 = uqn0; uq1 = uqn1;
            }
        }
        __syncthreads();
        B_row(bA, 0);
        B_row(bA + 1, 1);
        __syncthreads();
    };

    pair_body(ic<0>{}); pair_body(ic<1>{}); pair_body(ic<2>{});
    pair_body(ic<3>{}); pair_body(ic<4>{}); pair_body(ic<5>{});

    // epilogue: C of last pair (bufs 2,3)
    C_row(h0 + 10, 2, 0);
    C_row(h0 + 11, 3, 1);
}

// ---------------------------------------------------------------------------
extern "C" void kernel_launch(void* const* d_in, const int* in_sizes, int n_in,
                              void* d_out, int out_size, void* d_ws, size_t ws_size,
                              hipStream_t stream)
{
    const float* x0   = (const float*)d_in[0];  // (B,C,H,W) f32
    const float* spac = (const float*)d_in[1];  // (B,2)
    const float* sw   = (const float*)d_in[2];  // scalar
    const float* it   = (const float*)d_in[3];  // (2,)

    ushortT* tA  = (ushortT*)d_ws;              // 75.5 MB
    ushortT* tB  = tA + (size_t)NPIX;           // 75.5 MB
    ushortT* x0b = tB + (size_t)NPIX;           // 75.5 MB
    float*   out = (float*)d_out;

    dim3 gf(HSEGS, BB);   // (32,16) = 512 blocks
    dim3 bf(FT);

    // iter 1: t0 = ConvW(softmax(x0)); also emits x0b
    k_fused<0><<<gf, bf, 0, stream>>>(x0, nullptr, tA, x0b, spac, it, sw);
    // iters 2..5: t_{n+1} = ConvW(softmax(x0b + sw*ConvH(t_n)))
    k_fused<1><<<gf, bf, 0, stream>>>(tA, x0b, tB, nullptr, spac, it, sw);
    k_fused<1><<<gf, bf, 0, stream>>>(tB, x0b, tA, nullptr, spac, it, sw);
    k_fused<1><<<gf, bf, 0, stream>>>(tA, x0b, tB, nullptr, spac, it, sw);
    k_fused<1><<<gf, bf, 0, stream>>>(tB, x0b, tA, nullptr, spac, it, sw);
    // final: out = log_softmax(x0b + sw*ConvH(t4))
    k_fused<2><<<gf, bf, 0, stream>>>(tA, x0b, out, nullptr, spac, it, sw);
}